// Round 1
// baseline (337.744 us; speedup 1.0000x reference)
//
#include <hip/hip_runtime.h>
#include <hip/hip_bf16.h>
#include <math.h>

// Problem dims (fixed by reference)
#define BB 8
#define SS 8192
#define VV 64
#define DD 256
#define AGG_OUT 224   // D - DV

// ---- workspace layout (float/int32 slots, 4B each) ----
// total 55728 slots = 222,912 bytes
#define WS_FLAGS 0          // [0]=floatmode(1=bf16,0=f32) [1]=maskmode(0=i32,1=f32,2=bf16,3=u8)
#define WS_A     16         // a[224]
#define WS_C     240        // c[224]
#define WS_D     464        // d[224]
#define WS_AQ    688        // aq/cq/dq0 [256] each (dq0 WITHOUT bq)
#define WS_CQ    944
#define WS_DQ    1200
#define WS_AK    1456       // ak/ck/dk [256] (dk INCLUDES bk)
#define WS_CK    1712
#define WS_DK    1968
#define WS_AV    2224       // av/cv/dv [256] (dv INCLUDES bv)
#define WS_CV    2480
#define WS_DV    2736
#define WS_WQE   2992       // var_emb @ wq[0:32,:]  [64*256]
#define WS_WKE   19376
#define WS_WVE   35760
#define WS_CNT   52144      // int cnt[8*64]
#define WS_SV    52656      // sum vals [8*64]
#define WS_ST    53168      // sum times [8*64]
#define WS_CSUM  53680      // sum_v ctx  [8*256]

__device__ __forceinline__ float ldf(const void* p, int idx, int fm) {
  if (fm) {
    unsigned int u = ((const unsigned short*)p)[idx];
    return __uint_as_float(u << 16);
  }
  return ((const float*)p)[idx];
}

__device__ __forceinline__ bool mask_at(const void* p, int idx, int mm) {
  switch (mm) {
    case 0: return ((const int*)p)[idx] != 0;
    case 1: return ((const float*)p)[idx] != 0.0f;
    case 2: return ((const unsigned short*)p)[idx] != 0;
    default: return ((const unsigned char*)p)[idx] != 0;
  }
}

// K0: detect float width (from times ~ U(0,1)) and mask storage mode.
__global__ void k_detect(const void* times, const void* mask, float* ws) {
  __shared__ int cntR, f01, ff32, fbf;
  int tid = threadIdx.x;
  if (tid == 0) { cntR = 0; f01 = 1; ff32 = 1; fbf = 1; }
  __syncthreads();
  const unsigned int* tw = (const unsigned int*)times;
  int local = 0;
  for (int i = tid; i < 1024; i += 256) {
    unsigned int lo = tw[i] & 0xFFFFu;
    if (lo >= 0x3800u && lo < 0x3F80u) local++;   // bf16 pattern of (2^-15, 1)
  }
  atomicAdd(&cntR, local);
  const unsigned int* mw = (const unsigned int*)mask;
  int l01 = 1, lf32 = 1, lbf = 1;
  for (int i = tid; i < 2048; i += 256) {
    unsigned int w = mw[i];
    if (w > 1u) l01 = 0;
    if (!(w == 0u || w == 0x3F800000u)) lf32 = 0;
    unsigned int h0 = w & 0xFFFFu, h1 = w >> 16;
    if (!((h0 == 0u || h0 == 0x3F80u) && (h1 == 0u || h1 == 0x3F80u))) lbf = 0;
  }
  if (!l01) atomicAnd(&f01, 0);
  if (!lf32) atomicAnd(&ff32, 0);
  if (!lbf) atomicAnd(&fbf, 0);
  __syncthreads();
  if (tid == 0) {
    ((int*)ws)[0] = (cntR > 512) ? 1 : 0;
    ((int*)ws)[1] = f01 ? 0 : (ff32 ? 1 : (fbf ? 2 : 3));
  }
}

// K1: rank-2 collapse of eu@agg_w:  h_l[:,32+j] = vals*a[j] + times*c[j] + d[j]
__global__ void k_acd(const void* me_w, const void* me_b, const void* time_w,
                      const void* time_b, const void* agg_w, const void* agg_b,
                      float* ws) {
  int fm = ((const int*)ws)[0];
  int j = threadIdx.x;
  if (j >= AGG_OUT) return;
  float sa = 0.f, sc = 0.f, sd = 0.f;
  for (int i = 0; i < 256; i++) {
    float w0 = ldf(agg_w, i * AGG_OUT + j, fm);
    float w1 = ldf(agg_w, (256 + i) * AGG_OUT + j, fm);
    sa += ldf(me_w, i, fm) * w0;
    sc += ldf(time_w, i, fm) * w1;
    sd += ldf(me_b, i, fm) * w0 + ldf(time_b, i, fm) * w1;
  }
  ws[WS_A + j] = sa;
  ws[WS_C + j] = sc;
  ws[WS_D + j] = sd + ldf(agg_b, j, fm);
}

// K2: fold a/c/d through wq/wk/wv; embedding tables var_emb@wX[0:32,:]; zero csum.
__global__ void k_pre(const void* wq, const void* wk, const void* wv,
                      const void* bk, const void* bv, const void* var_emb,
                      float* ws) {
  int fm = ((const int*)ws)[0];
  int blk = blockIdx.x, d = threadIdx.x;
  if (blk < 3) {
    const void* w = (blk == 0) ? wq : (blk == 1) ? wk : wv;
    float sa = 0.f, sc = 0.f, sd = 0.f;
    for (int j = 0; j < AGG_OUT; j++) {
      float ww = ldf(w, (32 + j) * 256 + d, fm);
      sa += ws[WS_A + j] * ww;
      sc += ws[WS_C + j] * ww;
      sd += ws[WS_D + j] * ww;
    }
    if (blk == 1) sd += ldf(bk, d, fm);
    if (blk == 2) sd += ldf(bv, d, fm);
    int base = (blk == 0) ? WS_AQ : (blk == 1) ? WS_AK : WS_AV;
    ws[base + d] = sa;
    ws[base + 256 + d] = sc;
    ws[base + 512 + d] = sd;
  } else if (blk < 3 + 192) {
    int idx = blk - 3, X = idx >> 6, v = idx & 63;
    const void* w = (X == 0) ? wq : (X == 1) ? wk : wv;
    float s = 0.f;
    for (int i = 0; i < 32; i++)
      s += ldf(var_emb, v * 32 + i, fm) * ldf(w, i * 256 + d, fm);
    int base = (X == 0) ? WS_WQE : (X == 1) ? WS_WKE : WS_WVE;
    ws[base + v * 256 + d] = s;
  } else {
    for (int i = d; i < BB * 256; i += 256) ws[WS_CSUM + i] = 0.f;
  }
}

// K3: per-(b,v) segment stats: count, sum(vals), sum(times)
__global__ void __launch_bounds__(1024) k_stats(const void* values, const void* times,
                                                const int* fids, const void* mask,
                                                float* ws) {
  int fm = ((const int*)ws)[0], mm = ((const int*)ws)[1];
  int b = blockIdx.x, tid = threadIdx.x;
  __shared__ int cnt[64];
  __shared__ float sv[64], st[64];
  if (tid < 64) { cnt[tid] = 0; sv[tid] = 0.f; st[tid] = 0.f; }
  __syncthreads();
  for (int s = tid; s < SS; s += 1024) {
    int idx = b * SS + s;
    if (mask_at(mask, idx, mm)) {
      int f = fids[idx];
      atomicAdd(&cnt[f], 1);
      atomicAdd(&sv[f], ldf(values, idx, fm));
      atomicAdd(&st[f], ldf(times, idx, fm));
    }
  }
  __syncthreads();
  if (tid < 64) {
    ((int*)ws)[WS_CNT + b * 64 + tid] = cnt[tid];
    ws[WS_SV + b * 64 + tid] = sv[tid];
    ws[WS_ST + b * 64 + tid] = st[tid];
  }
}

// K4: attention per (b,v). Scores are affine in (vals,times):
//   score_h(s) = A_h + vals*B_h + times*C_h  (A,B,C from q dotted with tables)
// ctx needs only {Σw, Σw*vals, Σw*times} per head.
__global__ void __launch_bounds__(256) k_attn(const void* values, const void* times,
                                              const int* fids, const void* mask,
                                              const void* bq, float* ws) {
  int fm = ((const int*)ws)[0], mm = ((const int*)ws)[1];
  int bv = blockIdx.x, b = bv >> 6, v = bv & 63;
  int tid = threadIdx.x, h = tid >> 5, d = tid & 31;
  int cnt = ((const int*)ws)[WS_CNT + b * 64 + v];
  if (cnt == 0) {
    // empty variate: kpm unmasks position 0 -> attn=1 at s=0 -> ctx = v(s=0)
    int f0 = fids[b * SS];
    float v0 = ldf(values, b * SS, fm), t0 = ldf(times, b * SS, fm);
    float ctx = ws[WS_WVE + f0 * 256 + tid] + ws[WS_DV + tid]
              + v0 * ws[WS_AV + tid] + t0 * ws[WS_CV + tid];
    atomicAdd(&ws[WS_CSUM + b * 256 + tid], ctx);
    return;
  }
  float inv = 1.0f / (float)cnt;
  float mv = ws[WS_SV + b * 64 + v] * inv;
  float mt = ws[WS_ST + b * 64 + v] * inv;
  // q (scaled by 1/sqrt(32)) and per-head affine score coeffs
  float qv = ldf(bq, tid, fm) + ws[WS_WQE + v * 256 + tid]
           + mv * ws[WS_AQ + tid] + mt * ws[WS_CQ + tid] + ws[WS_DQ + tid];
  qv *= 0.17677669529663687f;
  float pA = qv * (ws[WS_WKE + v * 256 + tid] + ws[WS_DK + tid]);
  float pB = qv * ws[WS_AK + tid];
  float pC = qv * ws[WS_CK + tid];
  #pragma unroll
  for (int off = 16; off >= 1; off >>= 1) {
    pA += __shfl_xor(pA, off);
    pB += __shfl_xor(pB, off);
    pC += __shfl_xor(pC, off);
  }
  __shared__ float sA[8], sB[8], sC[8];
  if (d == 0) { sA[h] = pA; sB[h] = pB; sC[h] = pC; }
  __syncthreads();
  // pass1: per-head max over segment
  float lm[8];
  #pragma unroll
  for (int i = 0; i < 8; i++) lm[i] = -3.0e38f;
  for (int s = tid; s < SS; s += 256) {
    int idx = b * SS + s;
    if (fids[idx] == v && mask_at(mask, idx, mm)) {
      float val = ldf(values, idx, fm), tim = ldf(times, idx, fm);
      #pragma unroll
      for (int hh = 0; hh < 8; hh++)
        lm[hh] = fmaxf(lm[hh], sA[hh] + val * sB[hh] + tim * sC[hh]);
    }
  }
  #pragma unroll
  for (int hh = 0; hh < 8; hh++)
    for (int off = 32; off >= 1; off >>= 1)
      lm[hh] = fmaxf(lm[hh], __shfl_xor(lm[hh], off));
  __shared__ float wm[4][8];
  int wid = tid >> 6, lane = tid & 63;
  if (lane == 0)
    for (int hh = 0; hh < 8; hh++) wm[wid][hh] = lm[hh];
  __syncthreads();
  float m[8];
  #pragma unroll
  for (int hh = 0; hh < 8; hh++)
    m[hh] = fmaxf(fmaxf(wm[0][hh], wm[1][hh]), fmaxf(wm[2][hh], wm[3][hh]));
  // pass2: Σw, Σw*vals, Σw*times per head
  float W[8] = {0}, WVl[8] = {0}, WTl[8] = {0};
  for (int s = tid; s < SS; s += 256) {
    int idx = b * SS + s;
    if (fids[idx] == v && mask_at(mask, idx, mm)) {
      float val = ldf(values, idx, fm), tim = ldf(times, idx, fm);
      #pragma unroll
      for (int hh = 0; hh < 8; hh++) {
        float w = expf(sA[hh] + val * sB[hh] + tim * sC[hh] - m[hh]);
        W[hh] += w; WVl[hh] += w * val; WTl[hh] += w * tim;
      }
    }
  }
  #pragma unroll
  for (int hh = 0; hh < 8; hh++)
    for (int off = 32; off >= 1; off >>= 1) {
      W[hh]   += __shfl_xor(W[hh], off);
      WVl[hh] += __shfl_xor(WVl[hh], off);
      WTl[hh] += __shfl_xor(WTl[hh], off);
    }
  __shared__ float pW[4][8], pWV[4][8], pWT[4][8];
  if (lane == 0)
    for (int hh = 0; hh < 8; hh++) {
      pW[wid][hh] = W[hh]; pWV[wid][hh] = WVl[hh]; pWT[wid][hh] = WTl[hh];
    }
  __syncthreads();
  float Wh  = pW[0][h] + pW[1][h] + pW[2][h] + pW[3][h];
  float WVh = pWV[0][h] + pWV[1][h] + pWV[2][h] + pWV[3][h];
  float WTh = pWT[0][h] + pWT[1][h] + pWT[2][h] + pWT[3][h];
  float P = ws[WS_WVE + v * 256 + tid] + ws[WS_DV + tid];
  float ctx = (Wh * P + WVh * ws[WS_AV + tid] + WTh * ws[WS_CV + tid]) / Wh;
  atomicAdd(&ws[WS_CSUM + b * 256 + tid], ctx);
}

// K5: f = (csum/64)@wo + bo ; out = relu(f@cw1+cb1)@cw2 + cb2
__global__ void __launch_bounds__(256) k_fin(const void* wo, const void* bo,
                                             const void* cw1, const void* cb1,
                                             const void* cw2, const void* cb2,
                                             float* ws, void* out) {
  int fm = ((const int*)ws)[0];
  int b = blockIdx.x, tid = threadIdx.x;
  __shared__ float cs[256], fv[256];
  cs[tid] = ws[WS_CSUM + b * 256 + tid] * (1.0f / 64.0f);
  __syncthreads();
  float s = 0.f;
  for (int i = 0; i < 256; i++) s += cs[i] * ldf(wo, i * 256 + tid, fm);
  fv[tid] = s + ldf(bo, tid, fm);
  __syncthreads();
  float t = 0.f;
  for (int i = 0; i < 256; i++) t += fv[i] * ldf(cw1, i * 256 + tid, fm);
  t = fmaxf(t + ldf(cb1, tid, fm), 0.f);
  float p = t * ldf(cw2, tid, fm);
  #pragma unroll
  for (int off = 32; off >= 1; off >>= 1) p += __shfl_xor(p, off);
  __shared__ float pr[4];
  if ((tid & 63) == 0) pr[tid >> 6] = p;
  __syncthreads();
  if (tid == 0) {
    float o = pr[0] + pr[1] + pr[2] + pr[3] + ldf(cb2, 0, fm);
    if (fm) {
      unsigned int x = __float_as_uint(o);
      unsigned int r = (x + 0x7FFFu + ((x >> 16) & 1u)) >> 16;  // RNE
      ((unsigned short*)out)[b] = (unsigned short)r;
    } else {
      ((float*)out)[b] = o;
    }
  }
}

extern "C" void kernel_launch(void* const* d_in, const int* in_sizes, int n_in,
                              void* d_out, int out_size, void* d_ws, size_t ws_size,
                              hipStream_t stream) {
  const void* times   = d_in[0];
  const int*  fids    = (const int*)d_in[1];
  const void* values  = d_in[2];
  const void* vmask   = d_in[3];
  const void* me_w    = d_in[4];
  const void* me_b    = d_in[5];
  const void* var_emb = d_in[6];
  const void* time_w  = d_in[7];
  const void* time_b  = d_in[8];
  const void* agg_w   = d_in[9];
  const void* agg_b   = d_in[10];
  const void* wq = d_in[11]; const void* bq = d_in[12];
  const void* wk = d_in[13]; const void* bk = d_in[14];
  const void* wv = d_in[15]; const void* bv = d_in[16];
  const void* wo = d_in[17]; const void* bo = d_in[18];
  const void* cw1 = d_in[19]; const void* cb1 = d_in[20];
  const void* cw2 = d_in[21]; const void* cb2 = d_in[22];
  float* ws = (float*)d_ws;

  k_detect<<<1, 256, 0, stream>>>(times, vmask, ws);
  k_acd<<<1, 256, 0, stream>>>(me_w, me_b, time_w, time_b, agg_w, agg_b, ws);
  k_pre<<<196, 256, 0, stream>>>(wq, wk, wv, bk, bv, var_emb, ws);
  k_stats<<<8, 1024, 0, stream>>>(values, times, fids, vmask, ws);
  k_attn<<<512, 256, 0, stream>>>(values, times, fids, vmask, bq, ws);
  k_fin<<<8, 256, 0, stream>>>(wo, bo, cw1, cb1, cw2, cb2, ws, d_out);
}

// Round 2
// 177.694 us; speedup vs baseline: 1.9007x; 1.9007x over previous
//
#include <hip/hip_runtime.h>
#include <hip/hip_bf16.h>
#include <math.h>

// Problem dims (fixed by reference)
#define BB 8
#define SS 8192
#define VV 64
#define DD 256
#define AGG_OUT 224   // D - DV

// ---- workspace layout (float/int32 slots, 4B each) ----
#define WS_FLAGS 0          // [0]=floatmode(1=bf16,0=f32) [1]=maskmode(0=i32,1=f32,2=bf16,3=u8)
#define WS_A     16         // a[224]
#define WS_C     240        // c[224]
#define WS_D     464        // d[224]
#define WS_AQ    688        // aq/cq/dq0 [256] each (dq0 WITHOUT bq)
#define WS_CQ    944
#define WS_DQ    1200
#define WS_AK    1456       // ak/ck/dk [256] (dk INCLUDES bk)
#define WS_CK    1712
#define WS_DK    1968
#define WS_AV    2224       // av/cv/dv [256] (dv INCLUDES bv)
#define WS_CV    2480
#define WS_DV    2736
#define WS_WQE   2992       // var_emb @ wq[0:32,:]  [64*256]
#define WS_WKE   19376
#define WS_WVE   35760
#define WS_CSUM  53680      // sum_v ctx  [8*256]

__device__ __forceinline__ float ldf(const void* p, int idx, int fm) {
  if (fm) {
    unsigned int u = ((const unsigned short*)p)[idx];
    return __uint_as_float(u << 16);
  }
  return ((const float*)p)[idx];
}

__device__ __forceinline__ bool mask_at(const void* p, int idx, int mm) {
  switch (mm) {
    case 0: return ((const int*)p)[idx] != 0;
    case 1: return ((const float*)p)[idx] != 0.0f;
    case 2: return ((const unsigned short*)p)[idx] != 0;
    default: return ((const unsigned char*)p)[idx] != 0;
  }
}

// K0: detect float width (from times ~ U(0,1)) and mask storage mode; zero csum.
__global__ void k_detect(const void* times, const void* mask, float* ws) {
  __shared__ int cntR, f01, ff32, fbf;
  int tid = threadIdx.x;
  if (tid == 0) { cntR = 0; f01 = 1; ff32 = 1; fbf = 1; }
  __syncthreads();
  const unsigned int* tw = (const unsigned int*)times;
  int local = 0;
  for (int i = tid; i < 1024; i += 256) {
    unsigned int lo = tw[i] & 0xFFFFu;
    if (lo >= 0x3800u && lo < 0x3F80u) local++;   // bf16 pattern of (2^-15, 1)
  }
  atomicAdd(&cntR, local);
  const unsigned int* mw = (const unsigned int*)mask;
  int l01 = 1, lf32 = 1, lbf = 1;
  for (int i = tid; i < 2048; i += 256) {
    unsigned int w = mw[i];
    if (w > 1u) l01 = 0;
    if (!(w == 0u || w == 0x3F800000u)) lf32 = 0;
    unsigned int h0 = w & 0xFFFFu, h1 = w >> 16;
    if (!((h0 == 0u || h0 == 0x3F80u) && (h1 == 0u || h1 == 0x3F80u))) lbf = 0;
  }
  if (!l01) atomicAnd(&f01, 0);
  if (!lf32) atomicAnd(&ff32, 0);
  if (!lbf) atomicAnd(&fbf, 0);
  // zero the ctx accumulator (ws is poisoned 0xAA before every call)
  for (int i = tid; i < BB * 256; i += 256) ws[WS_CSUM + i] = 0.f;
  __syncthreads();
  if (tid == 0) {
    ((int*)ws)[0] = (cntR > 512) ? 1 : 0;
    ((int*)ws)[1] = f01 ? 0 : (ff32 ? 1 : (fbf ? 2 : 3));
  }
}

// K1: rank-2 collapse of eu@agg_w. Block j (224 blocks), 256 threads reduce over i.
__global__ void __launch_bounds__(256) k_acd(const void* me_w, const void* me_b,
                                             const void* time_w, const void* time_b,
                                             const void* agg_w, const void* agg_b,
                                             float* ws) {
  int fm = ((const int*)ws)[0];
  int j = blockIdx.x, i = threadIdx.x;
  float w0 = ldf(agg_w, i * AGG_OUT + j, fm);
  float w1 = ldf(agg_w, (256 + i) * AGG_OUT + j, fm);
  float sa = ldf(me_w, i, fm) * w0;
  float sc = ldf(time_w, i, fm) * w1;
  float sd = ldf(me_b, i, fm) * w0 + ldf(time_b, i, fm) * w1;
  #pragma unroll
  for (int off = 32; off >= 1; off >>= 1) {
    sa += __shfl_xor(sa, off);
    sc += __shfl_xor(sc, off);
    sd += __shfl_xor(sd, off);
  }
  __shared__ float r[3][4];
  int wid = i >> 6;
  if ((i & 63) == 0) { r[0][wid] = sa; r[1][wid] = sc; r[2][wid] = sd; }
  __syncthreads();
  if (i == 0) {
    ws[WS_A + j] = r[0][0] + r[0][1] + r[0][2] + r[0][3];
    ws[WS_C + j] = r[1][0] + r[1][1] + r[1][2] + r[1][3];
    ws[WS_D + j] = r[2][0] + r[2][1] + r[2][2] + r[2][3] + ldf(agg_b, j, fm);
  }
}

// K2: fold a/c/d through wq/wk/wv (24 blocks) + embedding tables (192 blocks).
__global__ void __launch_bounds__(256) k_pre(const void* wq, const void* wk,
                                             const void* wv, const void* bk,
                                             const void* bv, const void* var_emb,
                                             float* ws) {
  int fm = ((const int*)ws)[0];
  int blk = blockIdx.x, tid = threadIdx.x;
  if (blk < 24) {
    int X = blk >> 3, dg = blk & 7;
    const void* w = (X == 0) ? wq : (X == 1) ? wk : wv;
    __shared__ float sha[224], shc[224], shd[224];
    if (tid < 224) {
      sha[tid] = ws[WS_A + tid];
      shc[tid] = ws[WS_C + tid];
      shd[tid] = ws[WS_D + tid];
    }
    __syncthreads();
    int dsub = tid & 31, jg = tid >> 5;        // 32 d x 8 j-groups, 8*28 = 224
    int d = dg * 32 + dsub;
    float sa = 0.f, sc = 0.f, sd = 0.f;
    #pragma unroll 4
    for (int jj = 0; jj < 28; jj++) {
      int j = jg * 28 + jj;
      float ww = ldf(w, (32 + j) * 256 + d, fm);
      sa += sha[j] * ww; sc += shc[j] * ww; sd += shd[j] * ww;
    }
    __shared__ float ps[3][8][32];
    ps[0][jg][dsub] = sa; ps[1][jg][dsub] = sc; ps[2][jg][dsub] = sd;
    __syncthreads();
    if (tid < 32) {
      float ra = 0.f, rc = 0.f, rd = 0.f;
      #pragma unroll
      for (int g = 0; g < 8; g++) {
        ra += ps[0][g][tid]; rc += ps[1][g][tid]; rd += ps[2][g][tid];
      }
      int dd = dg * 32 + tid;
      if (X == 1) rd += ldf(bk, dd, fm);
      if (X == 2) rd += ldf(bv, dd, fm);
      int base = (X == 0) ? WS_AQ : (X == 1) ? WS_AK : WS_AV;
      ws[base + dd] = ra;
      ws[base + 256 + dd] = rc;
      ws[base + 512 + dd] = rd;
    }
  } else {
    int idx = blk - 24, X = idx >> 6, v = idx & 63, d = tid;
    const void* w = (X == 0) ? wq : (X == 1) ? wk : wv;
    float s = 0.f;
    #pragma unroll 8
    for (int i = 0; i < 32; i++)
      s += ldf(var_emb, v * 32 + i, fm) * ldf(w, i * 256 + d, fm);
    int base = (X == 0) ? WS_WQE : (X == 1) ? WS_WKE : WS_WVE;
    ws[base + v * 256 + d] = s;
  }
}

// K3: attention per (b,v), fully fused.
//  pass1: segment stats {cnt, Σval, Σtime} + val/time bounding box (softmax stabilizer)
//  coeffs: score_h(s) = A_h + val*B_h + time*C_h (affine collapse)
//  pass2: {Σw, Σw*val, Σw*time} per head, branch-free (additive -3e38 mask)
__global__ void __launch_bounds__(256) k_attn(const void* values, const void* times,
                                              const int* fids, const void* mask,
                                              const void* bq, float* ws) {
  int fm = ((const int*)ws)[0], mm = ((const int*)ws)[1];
  int bv = blockIdx.x, b = bv >> 6, v = bv & 63;
  int tid = threadIdx.x, h = tid >> 5;
  int wid = tid >> 6, lane = tid & 63;

  // ---- pass 1 ----
  int c = 0;
  float sv = 0.f, st = 0.f;
  float vmn = 3.0e38f, vmx = -3.0e38f, tmn = 3.0e38f, tmx = -3.0e38f;
  for (int s = tid; s < SS; s += 256) {
    int idx = b * SS + s;
    int f = fids[idx];
    bool pm = (f == v) && mask_at(mask, idx, mm);
    float val = ldf(values, idx, fm);
    float tim = ldf(times, idx, fm);
    if (pm) {
      c++; sv += val; st += tim;
      vmn = fminf(vmn, val); vmx = fmaxf(vmx, val);
      tmn = fminf(tmn, tim); tmx = fmaxf(tmx, tim);
    }
  }
  #pragma unroll
  for (int off = 32; off >= 1; off >>= 1) {
    c += __shfl_xor(c, off);
    sv += __shfl_xor(sv, off);
    st += __shfl_xor(st, off);
    vmn = fminf(vmn, __shfl_xor(vmn, off));
    vmx = fmaxf(vmx, __shfl_xor(vmx, off));
    tmn = fminf(tmn, __shfl_xor(tmn, off));
    tmx = fmaxf(tmx, __shfl_xor(tmx, off));
  }
  __shared__ float rs[7][4];
  if (lane == 0) {
    rs[0][wid] = (float)c; rs[1][wid] = sv; rs[2][wid] = st;
    rs[3][wid] = vmn; rs[4][wid] = vmx; rs[5][wid] = tmn; rs[6][wid] = tmx;
  }
  __syncthreads();
  float cT = rs[0][0] + rs[0][1] + rs[0][2] + rs[0][3];
  if (cT == 0.f) {
    // empty variate: kpm unmasks position 0 -> attn=1 at s=0 -> ctx = v(s=0)
    int f0 = fids[b * SS];
    float v0 = ldf(values, b * SS, fm), t0 = ldf(times, b * SS, fm);
    float ctx = ws[WS_WVE + f0 * 256 + tid] + ws[WS_DV + tid]
              + v0 * ws[WS_AV + tid] + t0 * ws[WS_CV + tid];
    atomicAdd(&ws[WS_CSUM + b * 256 + tid], ctx);
    return;
  }
  float svT = rs[1][0] + rs[1][1] + rs[1][2] + rs[1][3];
  float stT = rs[2][0] + rs[2][1] + rs[2][2] + rs[2][3];
  float vmnT = fminf(fminf(rs[3][0], rs[3][1]), fminf(rs[3][2], rs[3][3]));
  float vmxT = fmaxf(fmaxf(rs[4][0], rs[4][1]), fmaxf(rs[4][2], rs[4][3]));
  float tmnT = fminf(fminf(rs[5][0], rs[5][1]), fminf(rs[5][2], rs[5][3]));
  float tmxT = fmaxf(fmaxf(rs[6][0], rs[6][1]), fmaxf(rs[6][2], rs[6][3]));
  float inv = 1.0f / cT;
  float mv = svT * inv, mt = stT * inv;

  // ---- per-head affine score coefficients ----
  float qv = ldf(bq, tid, fm) + ws[WS_WQE + v * 256 + tid]
           + mv * ws[WS_AQ + tid] + mt * ws[WS_CQ + tid] + ws[WS_DQ + tid];
  qv *= 0.17677669529663687f;   // 1/sqrt(32)
  float pA = qv * (ws[WS_WKE + v * 256 + tid] + ws[WS_DK + tid]);
  float pB = qv * ws[WS_AK + tid];
  float pC = qv * ws[WS_CK + tid];
  #pragma unroll
  for (int off = 16; off >= 1; off >>= 1) {
    pA += __shfl_xor(pA, off);
    pB += __shfl_xor(pB, off);
    pC += __shfl_xor(pC, off);
  }
  __shared__ float sA[8], sB[8], sC[8];
  if ((tid & 31) == 0) { sA[h] = pA; sB[h] = pB; sC[h] = pC; }
  __syncthreads();
  // box upper bound on per-head max score (exact softmax via shift-invariance)
  float m[8];
  #pragma unroll
  for (int hh = 0; hh < 8; hh++)
    m[hh] = sA[hh] + fmaxf(sB[hh] * vmnT, sB[hh] * vmxT)
                   + fmaxf(sC[hh] * tmnT, sC[hh] * tmxT);

  // ---- pass 2 ----
  float W[8] = {0}, WVl[8] = {0}, WTl[8] = {0};
  for (int s = tid; s < SS; s += 256) {
    int idx = b * SS + s;
    int f = fids[idx];
    bool pm = (f == v) && mask_at(mask, idx, mm);
    float val = ldf(values, idx, fm);
    float tim = ldf(times, idx, fm);
    float nb = pm ? 0.f : -3.0e38f;
    #pragma unroll
    for (int hh = 0; hh < 8; hh++) {
      float w = expf(sA[hh] + val * sB[hh] + tim * sC[hh] - m[hh] + nb);
      W[hh] += w; WVl[hh] += w * val; WTl[hh] += w * tim;
    }
  }
  #pragma unroll
  for (int hh = 0; hh < 8; hh++)
    for (int off = 32; off >= 1; off >>= 1) {
      W[hh]   += __shfl_xor(W[hh], off);
      WVl[hh] += __shfl_xor(WVl[hh], off);
      WTl[hh] += __shfl_xor(WTl[hh], off);
    }
  __shared__ float pW[4][8], pWV[4][8], pWT[4][8];
  if (lane == 0)
    for (int hh = 0; hh < 8; hh++) {
      pW[wid][hh] = W[hh]; pWV[wid][hh] = WVl[hh]; pWT[wid][hh] = WTl[hh];
    }
  __syncthreads();
  float Wh  = pW[0][h] + pW[1][h] + pW[2][h] + pW[3][h];
  float WVh = pWV[0][h] + pWV[1][h] + pWV[2][h] + pWV[3][h];
  float WTh = pWT[0][h] + pWT[1][h] + pWT[2][h] + pWT[3][h];
  float P = ws[WS_WVE + v * 256 + tid] + ws[WS_DV + tid];
  float ctx = (Wh * P + WVh * ws[WS_AV + tid] + WTh * ws[WS_CV + tid]) / Wh;
  atomicAdd(&ws[WS_CSUM + b * 256 + tid], ctx);
}

// K4: f = (csum/64)@wo + bo ; out = relu(f@cw1+cb1)@cw2 + cb2
// 8 blocks x 1024 threads: 256 d x 4 i-groups, LDS reduce.
__global__ void __launch_bounds__(1024) k_fin(const void* wo, const void* bo,
                                              const void* cw1, const void* cb1,
                                              const void* cw2, const void* cb2,
                                              float* ws, void* out) {
  int fm = ((const int*)ws)[0];
  int b = blockIdx.x, tid = threadIdx.x;
  int d = tid & 255, ig = tid >> 8;
  __shared__ float cs[256], fv[256], ps[4][256], pr[16];
  if (tid < 256) cs[tid] = ws[WS_CSUM + b * 256 + tid] * (1.0f / 64.0f);
  __syncthreads();
  float s = 0.f;
  #pragma unroll 8
  for (int k = 0; k < 64; k++) {
    int i = ig * 64 + k;
    s += cs[i] * ldf(wo, i * 256 + d, fm);
  }
  ps[ig][d] = s;
  __syncthreads();
  if (tid < 256) fv[tid] = ps[0][tid] + ps[1][tid] + ps[2][tid] + ps[3][tid]
                         + ldf(bo, tid, fm);
  __syncthreads();
  float t2 = 0.f;
  #pragma unroll 8
  for (int k = 0; k < 64; k++) {
    int i = ig * 64 + k;
    t2 += fv[i] * ldf(cw1, i * 256 + d, fm);
  }
  ps[ig][d] = t2;
  __syncthreads();
  float p = 0.f;
  if (tid < 256) {
    float t = ps[0][tid] + ps[1][tid] + ps[2][tid] + ps[3][tid] + ldf(cb1, tid, fm);
    t = fmaxf(t, 0.f);
    p = t * ldf(cw2, tid, fm);
  }
  #pragma unroll
  for (int off = 32; off >= 1; off >>= 1) p += __shfl_xor(p, off);
  if ((tid & 63) == 0) pr[tid >> 6] = p;
  __syncthreads();
  if (tid == 0) {
    float o = ldf(cb2, 0, fm);
    #pragma unroll
    for (int wgi = 0; wgi < 16; wgi++) o += pr[wgi];
    if (fm) {
      unsigned int x = __float_as_uint(o);
      unsigned int r = (x + 0x7FFFu + ((x >> 16) & 1u)) >> 16;  // RNE
      ((unsigned short*)out)[b] = (unsigned short)r;
    } else {
      ((float*)out)[b] = o;
    }
  }
}

extern "C" void kernel_launch(void* const* d_in, const int* in_sizes, int n_in,
                              void* d_out, int out_size, void* d_ws, size_t ws_size,
                              hipStream_t stream) {
  const void* times   = d_in[0];
  const int*  fids    = (const int*)d_in[1];
  const void* values  = d_in[2];
  const void* vmask   = d_in[3];
  const void* me_w    = d_in[4];
  const void* me_b    = d_in[5];
  const void* var_emb = d_in[6];
  const void* time_w  = d_in[7];
  const void* time_b  = d_in[8];
  const void* agg_w   = d_in[9];
  const void* agg_b   = d_in[10];
  const void* wq = d_in[11]; const void* bq = d_in[12];
  const void* wk = d_in[13]; const void* bk = d_in[14];
  const void* wv = d_in[15]; const void* bv = d_in[16];
  const void* wo = d_in[17]; const void* bo = d_in[18];
  const void* cw1 = d_in[19]; const void* cb1 = d_in[20];
  const void* cw2 = d_in[21]; const void* cb2 = d_in[22];
  float* ws = (float*)d_ws;

  k_detect<<<1, 256, 0, stream>>>(times, vmask, ws);
  k_acd<<<224, 256, 0, stream>>>(me_w, me_b, time_w, time_b, agg_w, agg_b, ws);
  k_pre<<<216, 256, 0, stream>>>(wq, wk, wv, bk, bv, var_emb, ws);
  k_attn<<<512, 256, 0, stream>>>(values, times, fids, vmask, bq, ws);
  k_fin<<<8, 256 * 4, 0, stream>>>(wo, bo, cw1, cb1, cw2, cb2, ws, d_out);
}

// Round 3
// 149.704 us; speedup vs baseline: 2.2561x; 1.1870x over previous
//
#include <hip/hip_runtime.h>
#include <hip/hip_bf16.h>
#include <math.h>

// Problem dims (fixed by reference)
#define BB 8
#define SS 8192
#define VV 64
#define AGG_OUT 224   // D - DV

// ---- workspace layout (float/int32 slots, 4B each) ----  total 115632 floats = 463 KB
#define WS_FLAGS 0          // [0]=floatmode(1=bf16,0=f32) [1]=maskmode(0=i32,1=f32,2=bf16,3=u8)
#define WS_A     16         // a[224]
#define WS_C     240
#define WS_D     464
#define WS_AQ    688        // aq/cq/dq0 [256] each
#define WS_CQ    944
#define WS_DQ    1200
#define WS_AK    1456       // ak/ck/dk [256] (dk includes bk)
#define WS_CK    1712
#define WS_DK    1968
#define WS_AV    2224       // av/cv/dv [256] (dv includes bv)
#define WS_CV    2480
#define WS_DV    2736
#define WS_WQE   2992       // var_emb @ wq[0:32,:]  [64*256]
#define WS_WKE   19376
#define WS_WVE   35760
#define WS_CSUM  52144      // [8*256] ctx accumulator (empty-variate path adds here)
#define WS_BINS  54192      // [8*64*24] (b*64+v)*24 + h*3 + {W,WV,WT}  (zeroed in K1)
#define WS_COEF  66480      // [8*64*8*4] (bv*8+h)*4 + {A,B,C,m}  (log2e-scaled)
#define WS_SP    82864      // [64 slices * 64 v * 8] stats partials

__device__ __forceinline__ float ldf(const void* p, int idx, int fm) {
  if (fm) {
    unsigned int u = ((const unsigned short*)p)[idx];
    return __uint_as_float(u << 16);
  }
  return ((const float*)p)[idx];
}

__device__ __forceinline__ bool mask_at(const void* p, int idx, int mm) {
  switch (mm) {
    case 0: return ((const int*)p)[idx] != 0;
    case 1: return ((const float*)p)[idx] != 0.0f;
    case 2: return ((const unsigned short*)p)[idx] != 0;
    default: return ((const unsigned char*)p)[idx] != 0;
  }
}

// order-preserving float<->uint key (for atomicMin/Max on LDS uints)
__device__ __forceinline__ unsigned int fkey(float f) {
  unsigned int u = __float_as_uint(f);
  return (u & 0x80000000u) ? ~u : (u | 0x80000000u);
}
__device__ __forceinline__ float funkey(unsigned int k) {
  unsigned int u = (k & 0x80000000u) ? (k ^ 0x80000000u) : ~k;
  return __uint_as_float(u);
}

__device__ __forceinline__ int detect_fm_block(const void* times) {
  __shared__ int cntR;
  int tid = threadIdx.x;
  if (tid == 0) cntR = 0;
  __syncthreads();
  const unsigned int* tw = (const unsigned int*)times;
  int local = 0;
  for (int i = tid; i < 1024; i += 256) {
    unsigned int lo = tw[i] & 0xFFFFu;
    if (lo >= 0x3800u && lo < 0x3F80u) local++;   // bf16 pattern of U(0,1)
  }
  atomicAdd(&cntR, local);
  __syncthreads();
  int r = (cntR > 512) ? 1 : 0;
  __syncthreads();
  return r;
}

__device__ __forceinline__ int detect_mm_block(const void* mask) {
  __shared__ int f01, ff32, fbf;
  int tid = threadIdx.x;
  if (tid == 0) { f01 = 1; ff32 = 1; fbf = 1; }
  __syncthreads();
  const unsigned int* mw = (const unsigned int*)mask;
  int l01 = 1, lf32 = 1, lbf = 1;
  for (int i = tid; i < 2048; i += 256) {
    unsigned int w = mw[i];
    if (w > 1u) l01 = 0;
    if (!(w == 0u || w == 0x3F800000u)) lf32 = 0;
    unsigned int h0 = w & 0xFFFFu, h1 = w >> 16;
    if (!((h0 == 0u || h0 == 0x3F80u) && (h1 == 0u || h1 == 0x3F80u))) lbf = 0;
  }
  if (!l01) atomicAnd(&f01, 0);
  if (!lf32) atomicAnd(&ff32, 0);
  if (!lbf) atomicAnd(&fbf, 0);
  __syncthreads();
  int r = f01 ? 0 : (ff32 ? 1 : (fbf ? 2 : 3));
  __syncthreads();
  return r;
}

// K1: blocks 0..223 acd-collapse; 224..287 per-(b,chunk) segment stats histograms;
//     288..295 zero CSUM+BINS (blk 288 also publishes flags).
__global__ void __launch_bounds__(256) k_front(const void* times, const void* values,
                                               const int* fids, const void* mask,
                                               const void* me_w, const void* me_b,
                                               const void* time_w, const void* time_b,
                                               const void* agg_w, const void* agg_b,
                                               float* ws) {
  int blk = blockIdx.x, tid = threadIdx.x;
  if (blk < 224) {
    int fm = detect_fm_block(times);
    int j = blk, i = tid;
    float w0 = ldf(agg_w, i * AGG_OUT + j, fm);
    float w1 = ldf(agg_w, (256 + i) * AGG_OUT + j, fm);
    float sa = ldf(me_w, i, fm) * w0;
    float sc = ldf(time_w, i, fm) * w1;
    float sd = ldf(me_b, i, fm) * w0 + ldf(time_b, i, fm) * w1;
    #pragma unroll
    for (int off = 32; off >= 1; off >>= 1) {
      sa += __shfl_xor(sa, off);
      sc += __shfl_xor(sc, off);
      sd += __shfl_xor(sd, off);
    }
    __shared__ float r[3][4];
    int wid = i >> 6;
    if ((i & 63) == 0) { r[0][wid] = sa; r[1][wid] = sc; r[2][wid] = sd; }
    __syncthreads();
    if (i == 0) {
      ws[WS_A + j] = r[0][0] + r[0][1] + r[0][2] + r[0][3];
      ws[WS_C + j] = r[1][0] + r[1][1] + r[1][2] + r[1][3];
      ws[WS_D + j] = r[2][0] + r[2][1] + r[2][2] + r[2][3] + ldf(agg_b, j, fm);
    }
  } else if (blk < 288) {
    int fm = detect_fm_block(times);
    int mm = detect_mm_block(mask);
    int sblk = blk - 224, b = sblk >> 3, chunk = sblk & 7;
    __shared__ float hc[64], hsv[64], hst[64];
    __shared__ unsigned int hvn[64], hvx[64], htn[64], htx[64];
    if (tid < 64) {
      hc[tid] = 0.f; hsv[tid] = 0.f; hst[tid] = 0.f;
      hvn[tid] = 0xFFFFFFFFu; hvx[tid] = 0u;
      htn[tid] = 0xFFFFFFFFu; htx[tid] = 0u;
    }
    __syncthreads();
    #pragma unroll
    for (int k = 0; k < 4; k++) {
      int idx = b * SS + chunk * 1024 + k * 256 + tid;
      if (mask_at(mask, idx, mm)) {
        int f = fids[idx];
        float val = ldf(values, idx, fm), tim = ldf(times, idx, fm);
        atomicAdd(&hc[f], 1.0f);
        atomicAdd(&hsv[f], val);
        atomicAdd(&hst[f], tim);
        unsigned int vk = fkey(val), tk = fkey(tim);
        atomicMin(&hvn[f], vk); atomicMax(&hvx[f], vk);
        atomicMin(&htn[f], tk); atomicMax(&htx[f], tk);
      }
    }
    __syncthreads();
    if (tid < 64) {
      int base = WS_SP + (sblk * 64 + tid) * 8;
      ws[base + 0] = hc[tid];
      ws[base + 1] = hsv[tid];
      ws[base + 2] = hst[tid];
      ((unsigned int*)ws)[base + 3] = hvn[tid];
      ((unsigned int*)ws)[base + 4] = hvx[tid];
      ((unsigned int*)ws)[base + 5] = htn[tid];
      ((unsigned int*)ws)[base + 6] = htx[tid];
    }
  } else {
    int zblk = blk - 288;
    for (int i = zblk * 256 + tid; i < 14336; i += 2048) ws[WS_CSUM + i] = 0.f;
    if (zblk == 0) {
      int fm = detect_fm_block(times);
      int mm = detect_mm_block(mask);
      if (tid == 0) { ((int*)ws)[0] = fm; ((int*)ws)[1] = mm; }
    }
  }
}

// K2: fold a/c/d through wq/wk/wv (24 blocks) + embedding tables (192 blocks).
__global__ void __launch_bounds__(256) k_pre(const void* wq, const void* wk,
                                             const void* wv, const void* bk,
                                             const void* bv, const void* var_emb,
                                             float* ws) {
  int fm = ((const int*)ws)[0];
  int blk = blockIdx.x, tid = threadIdx.x;
  if (blk < 24) {
    int X = blk >> 3, dg = blk & 7;
    const void* w = (X == 0) ? wq : (X == 1) ? wk : wv;
    __shared__ float sha[224], shc[224], shd[224];
    if (tid < 224) {
      sha[tid] = ws[WS_A + tid];
      shc[tid] = ws[WS_C + tid];
      shd[tid] = ws[WS_D + tid];
    }
    __syncthreads();
    int dsub = tid & 31, jg = tid >> 5;
    int d = dg * 32 + dsub;
    float sa = 0.f, sc = 0.f, sd = 0.f;
    #pragma unroll 4
    for (int jj = 0; jj < 28; jj++) {
      int j = jg * 28 + jj;
      float ww = ldf(w, (32 + j) * 256 + d, fm);
      sa += sha[j] * ww; sc += shc[j] * ww; sd += shd[j] * ww;
    }
    __shared__ float ps[3][8][32];
    ps[0][jg][dsub] = sa; ps[1][jg][dsub] = sc; ps[2][jg][dsub] = sd;
    __syncthreads();
    if (tid < 32) {
      float ra = 0.f, rc = 0.f, rd = 0.f;
      #pragma unroll
      for (int g = 0; g < 8; g++) {
        ra += ps[0][g][tid]; rc += ps[1][g][tid]; rd += ps[2][g][tid];
      }
      int dd = dg * 32 + tid;
      if (X == 1) rd += ldf(bk, dd, fm);
      if (X == 2) rd += ldf(bv, dd, fm);
      int base = (X == 0) ? WS_AQ : (X == 1) ? WS_AK : WS_AV;
      ws[base + dd] = ra;
      ws[base + 256 + dd] = rc;
      ws[base + 512 + dd] = rd;
    }
  } else {
    int idx = blk - 24, X = idx >> 6, v = idx & 63, d = tid;
    const void* w = (X == 0) ? wq : (X == 1) ? wk : wv;
    float s = 0.f;
    #pragma unroll 8
    for (int i = 0; i < 32; i++)
      s += ldf(var_emb, v * 32 + i, fm) * ldf(w, i * 256 + d, fm);
    int base = (X == 0) ? WS_WQE : (X == 1) ? WS_WKE : WS_WVE;
    ws[base + v * 256 + d] = s;
  }
}

// K3: per-(b,v) affine score coefficients, log2e-prescaled, + box max m.
//     Empty variates contribute ctx directly into CSUM here.
__global__ void __launch_bounds__(256) k_coef(const void* values, const void* times,
                                              const int* fids, const void* bq,
                                              float* ws) {
  int fm = ((const int*)ws)[0];
  int bv = blockIdx.x, b = bv >> 6, v = bv & 63;
  int tid = threadIdx.x, h = tid >> 5;
  __shared__ float sp[8][8];
  if (tid < 64) {
    int sl = tid >> 3, c = tid & 7;
    sp[sl][c] = ws[WS_SP + ((b * 8 + sl) * 64 + v) * 8 + c];
  }
  __syncthreads();
  float cT = 0.f, svT = 0.f, stT = 0.f;
  unsigned int vnk = 0xFFFFFFFFu, vxk = 0u, tnk = 0xFFFFFFFFu, txk = 0u;
  #pragma unroll
  for (int sl = 0; sl < 8; sl++) {
    cT += sp[sl][0]; svT += sp[sl][1]; stT += sp[sl][2];
    unsigned int a3 = __float_as_uint(sp[sl][3]);
    unsigned int a4 = __float_as_uint(sp[sl][4]);
    unsigned int a5 = __float_as_uint(sp[sl][5]);
    unsigned int a6 = __float_as_uint(sp[sl][6]);
    vnk = min(vnk, a3); vxk = max(vxk, a4);
    tnk = min(tnk, a5); txk = max(txk, a6);
  }
  if (cT == 0.f) {
    // kpm unmasks position 0 -> attn=1 at s=0 -> ctx = v(s=0)
    int f0 = fids[b * SS];
    float v0 = ldf(values, b * SS, fm), t0 = ldf(times, b * SS, fm);
    float ctx = ws[WS_WVE + f0 * 256 + tid] + ws[WS_DV + tid]
              + v0 * ws[WS_AV + tid] + t0 * ws[WS_CV + tid];
    atomicAdd(&ws[WS_CSUM + b * 256 + tid], ctx);
    return;
  }
  float inv = 1.0f / cT, mv = svT * inv, mt = stT * inv;
  float qv = ldf(bq, tid, fm) + ws[WS_WQE + v * 256 + tid]
           + mv * ws[WS_AQ + tid] + mt * ws[WS_CQ + tid] + ws[WS_DQ + tid];
  qv *= 0.17677669529663687f * 1.4426950408889634f;  // 1/sqrt(32) * log2(e)
  float pA = qv * (ws[WS_WKE + v * 256 + tid] + ws[WS_DK + tid]);
  float pB = qv * ws[WS_AK + tid];
  float pC = qv * ws[WS_CK + tid];
  #pragma unroll
  for (int off = 16; off >= 1; off >>= 1) {
    pA += __shfl_xor(pA, off);
    pB += __shfl_xor(pB, off);
    pC += __shfl_xor(pC, off);
  }
  if ((tid & 31) == 0) {
    float vmn = funkey(vnk), vmx = funkey(vxk);
    float tmn = funkey(tnk), tmx = funkey(txk);
    float m = pA + fmaxf(pB * vmn, pB * vmx) + fmaxf(pC * tmn, pC * tmx);
    int base = WS_COEF + (bv * 8 + h) * 4;
    ws[base + 0] = pA; ws[base + 1] = pB; ws[base + 2] = pC; ws[base + 3] = m;
  }
}

// K4: single segmented-accumulation scan. 128 blocks (16 per b-row, 512 elem each).
// Per valid element: 8 heads x {w=exp2(...), 3 LDS atomic adds}; flush nonzero bins.
__global__ void __launch_bounds__(256) k_accum(const void* values, const void* times,
                                               const int* fids, const void* mask,
                                               float* ws) {
  int fm = ((const int*)ws)[0], mm = ((const int*)ws)[1];
  int blk = blockIdx.x, tid = threadIdx.x;
  int b = blk >> 4, chunk = blk & 15;
  __shared__ float co[64 * 36];    // padded: v*36 + h*4 + c  (bank spread)
  __shared__ float bins[64 * 25];  // padded: v*25 + h*3 + c
  for (int i = tid; i < 2048; i += 256) {
    int v = i >> 5, r = i & 31;
    co[v * 36 + r] = ws[WS_COEF + b * 2048 + i];
  }
  for (int i = tid; i < 1600; i += 256) bins[i] = 0.f;
  __syncthreads();
  #pragma unroll
  for (int k = 0; k < 2; k++) {
    int idx = b * SS + chunk * 512 + k * 256 + tid;
    if (mask_at(mask, idx, mm)) {
      int f = fids[idx];
      float val = ldf(values, idx, fm), tim = ldf(times, idx, fm);
      #pragma unroll
      for (int h = 0; h < 8; h++) {
        int cb = f * 36 + h * 4;
        float w = exp2f(co[cb] + val * co[cb + 1] + tim * co[cb + 2] - co[cb + 3]);
        int bb = f * 25 + h * 3;
        atomicAdd(&bins[bb], w);
        atomicAdd(&bins[bb + 1], w * val);
        atomicAdd(&bins[bb + 2], w * tim);
      }
    }
  }
  __syncthreads();
  for (int i = tid; i < 1536; i += 256) {
    int f = i / 24, r = i - f * 24;
    float x = bins[f * 25 + r];
    if (x != 0.f) atomicAdd(&ws[WS_BINS + b * 1536 + i], x);
  }
}

// K5: normalize bins, sum ctx over v, then f@wo+bo -> MLP -> out.
__global__ void __launch_bounds__(1024) k_fin(const void* wo, const void* bo,
                                              const void* cw1, const void* cb1,
                                              const void* cw2, const void* cb2,
                                              float* ws, void* out) {
  int fm = ((const int*)ws)[0];
  int b = blockIdx.x, tid = threadIdx.x;
  __shared__ float aa[64][9], tt[64][9], ne[64];
  __shared__ float ps[4][256], cs[256], fv[256], pr[16];
  if (tid < 512) {
    int v = tid >> 3, h = tid & 7;
    int base = WS_BINS + b * 1536 + v * 24 + h * 3;
    float W = ws[base], WV = ws[base + 1], WT = ws[base + 2];
    float iW = (W > 0.f) ? 1.0f / W : 0.f;
    aa[v][h] = WV * iW; tt[v][h] = WT * iW;
    if (h == 0) ne[v] = (W > 0.f) ? 1.f : 0.f;
  }
  __syncthreads();
  int d = tid & 255, vg = tid >> 8, h = d >> 5;
  float accP = 0.f, accA = 0.f, accT = 0.f, accN = 0.f;
  #pragma unroll 4
  for (int k = 0; k < 16; k++) {
    int v = vg * 16 + k;
    float nef = ne[v];
    accP += nef * ws[WS_WVE + v * 256 + d];
    accA += aa[v][h];    // zero for empty v
    accT += tt[v][h];
    accN += nef;
  }
  ps[vg][d] = accP + accN * ws[WS_DV + d] + accA * ws[WS_AV + d] + accT * ws[WS_CV + d];
  __syncthreads();
  if (tid < 256)
    cs[tid] = (ws[WS_CSUM + b * 256 + tid] + ps[0][tid] + ps[1][tid]
             + ps[2][tid] + ps[3][tid]) * (1.0f / 64.0f);
  __syncthreads();
  float s = 0.f;
  #pragma unroll 8
  for (int k = 0; k < 64; k++) {
    int i = vg * 64 + k;
    s += cs[i] * ldf(wo, i * 256 + d, fm);
  }
  ps[vg][d] = s;
  __syncthreads();
  if (tid < 256) fv[tid] = ps[0][tid] + ps[1][tid] + ps[2][tid] + ps[3][tid]
                         + ldf(bo, tid, fm);
  __syncthreads();
  float t2 = 0.f;
  #pragma unroll 8
  for (int k = 0; k < 64; k++) {
    int i = vg * 64 + k;
    t2 += fv[i] * ldf(cw1, i * 256 + d, fm);
  }
  ps[vg][d] = t2;
  __syncthreads();
  float p = 0.f;
  if (tid < 256) {
    float t = ps[0][tid] + ps[1][tid] + ps[2][tid] + ps[3][tid] + ldf(cb1, tid, fm);
    t = fmaxf(t, 0.f);
    p = t * ldf(cw2, tid, fm);
  }
  #pragma unroll
  for (int off = 32; off >= 1; off >>= 1) p += __shfl_xor(p, off);
  if ((tid & 63) == 0) pr[tid >> 6] = p;
  __syncthreads();
  if (tid == 0) {
    float o = ldf(cb2, 0, fm);
    #pragma unroll
    for (int wgi = 0; wgi < 16; wgi++) o += pr[wgi];
    if (fm) {
      unsigned int x = __float_as_uint(o);
      unsigned int r = (x + 0x7FFFu + ((x >> 16) & 1u)) >> 16;  // RNE
      ((unsigned short*)out)[b] = (unsigned short)r;
    } else {
      ((float*)out)[b] = o;
    }
  }
}

extern "C" void kernel_launch(void* const* d_in, const int* in_sizes, int n_in,
                              void* d_out, int out_size, void* d_ws, size_t ws_size,
                              hipStream_t stream) {
  const void* times   = d_in[0];
  const int*  fids    = (const int*)d_in[1];
  const void* values  = d_in[2];
  const void* vmask   = d_in[3];
  const void* me_w    = d_in[4];
  const void* me_b    = d_in[5];
  const void* var_emb = d_in[6];
  const void* time_w  = d_in[7];
  const void* time_b  = d_in[8];
  const void* agg_w   = d_in[9];
  const void* agg_b   = d_in[10];
  const void* wq = d_in[11]; const void* bq = d_in[12];
  const void* wk = d_in[13]; const void* bk = d_in[14];
  const void* wv = d_in[15]; const void* bv = d_in[16];
  const void* wo = d_in[17]; const void* bo = d_in[18];
  const void* cw1 = d_in[19]; const void* cb1 = d_in[20];
  const void* cw2 = d_in[21]; const void* cb2 = d_in[22];
  float* ws = (float*)d_ws;

  k_front<<<296, 256, 0, stream>>>(times, values, fids, vmask,
                                   me_w, me_b, time_w, time_b, agg_w, agg_b, ws);
  k_pre<<<216, 256, 0, stream>>>(wq, wk, wv, bk, bv, var_emb, ws);
  k_coef<<<512, 256, 0, stream>>>(values, times, fids, bq, ws);
  k_accum<<<128, 256, 0, stream>>>(values, times, fids, vmask, ws);
  k_fin<<<8, 1024, 0, stream>>>(wo, bo, cw1, cb1, cw2, cb2, ws, d_out);
}